// Round 5
// baseline (216.876 us; speedup 1.0000x reference)
//
#include <hip/hip_runtime.h>

typedef _Float16 f16;
typedef __attribute__((ext_vector_type(4))) _Float16 f16x4;
typedef __attribute__((ext_vector_type(8))) _Float16 f16x8;
typedef __attribute__((ext_vector_type(4))) float f32x4;

#define MFMA16(a, b, c) __builtin_amdgcn_mfma_f32_16x16x32_f16((a), (b), (c), 0, 0, 0)

__device__ __forceinline__ f16x8 cvt8(float4 a, float4 b) {
    f16x8 r;
    r[0] = (f16)a.x; r[1] = (f16)a.y; r[2] = (f16)a.z; r[3] = (f16)a.w;
    r[4] = (f16)b.x; r[5] = (f16)b.y; r[6] = (f16)b.z; r[7] = (f16)b.w;
    return r;
}

__device__ __forceinline__ f16x8 zero8() {
    f16x8 z;
#pragma unroll
    for (int q = 0; q < 8; ++q) z[q] = (f16)0.0f;
    return z;
}

// ---------------- pre-kernel: fp16 weights + fused bias constants into ws ----
__global__ void prep_kernel(const float* __restrict__ w_ih, const float* __restrict__ w_hh,
                            const float* __restrict__ b_ih, const float* __restrict__ b_hh,
                            const float* __restrict__ b_iah, const float* __restrict__ b_oah,
                            const float* __restrict__ W_in, const float* __restrict__ bias_in,
                            const float* __restrict__ W_out, const float* __restrict__ bias_out,
                            f16* __restrict__ Wc, f16* __restrict__ Whh, f16* __restrict__ Wih,
                            float* __restrict__ cstA, float* __restrict__ cstB,
                            float* __restrict__ biasc) {
    const int gid = blockIdx.x * 256 + threadIdx.x;
    const int gstride = gridDim.x * 256;
    for (int i = gid; i < 8192; i += gstride)
        Wc[i] = (f16)(i < 4096 ? W_in[i] : W_out[i - 4096]);
    for (int i = gid; i < 12288; i += gstride) Whh[i] = (f16)w_hh[i];   // [192][64]
    for (int i = gid; i < 24576; i += gstride) Wih[i] = (f16)w_ih[i];   // [192][128]
    for (int job = gid; job < 768; job += gstride) {
        const int g = job >> 2, q = job & 3;
        float s = (q == 0) ? b_ih[g] : 0.0f;
        const float* wr = w_ih + g * 128 + q * 32;
        for (int i = 0; i < 32; ++i)
            s += wr[i] * ((q * 32 + i < 64) ? b_iah[q * 32 + i] : b_oah[q * 32 + i - 64]);
        atomicAdd(&cstA[g], s);
    }
    for (int g = gid; g < 192; g += gstride) cstB[g] = b_hh[g];
    for (int j = gid; j < 128; j += gstride) biasc[j] = (j < 64) ? bias_in[j] : bias_out[j - 64];
}

__global__ void zero_kernel(float* __restrict__ cstA) {
    if (threadIdx.x < 192) cstA[threadIdx.x] = 0.0f;
}

// ---------------- fused main kernel: one WG (512 thr) per batch b ------------
// LDS 51712 B (aliased):
//   phase 1:  hT [128 cols][202 m] f16   (dead after B-frag hoist)
//   phase 2:  hA [2 buf][64 rows][202 m] f16  (2 halves x 32 n-rows per buf)
// Phase-2 accumulators spill per-iter to global inp (f16, same-WG L2-hot).
__global__ __launch_bounds__(512, 4) void gru_fused(
    const float* __restrict__ A, const float* __restrict__ hidden,
    const f16* __restrict__ Wc, const f16* __restrict__ Whh, const f16* __restrict__ Wih,
    const float* __restrict__ cstA, const float* __restrict__ cstB,
    const float* __restrict__ biasc, f16* __restrict__ inp, float* __restrict__ out) {
    __shared__ __align__(16) char lds_raw[51712];
    f16* hT = (f16*)lds_raw;   // [128][202]
    f16* hA = (f16*)lds_raw;   // [2][64][202] alias

    const int b = blockIdx.x;
    const float* Ab = A + (size_t)b * 80000;      // [400][200]
    const float* hb = hidden + (size_t)b * 12800; // [200][64]
    f16* ib = inp + (size_t)b * 25600;            // [200][128]
    float* ob = out + (size_t)b * 12800;

    const int tid = threadIdx.x;
    const int w   = tid >> 6;
    const int l   = tid & 63;
    const int l15 = l & 15;
    const int lg  = l >> 4;

    // ---- Phase 1: hT[j][m] = f16(hidden[m,:]@Wc[j,:] + biasc[j]), stride 202
    for (int mt = w; mt < 13; mt += 8) {
        const int m  = mt * 16 + l15;
        const int mc = m < 200 ? m : 199;
        const float* hrow = hb + mc * 64;
        float4 r0 = *(const float4*)(hrow + lg * 8);
        float4 r1 = *(const float4*)(hrow + lg * 8 + 4);
        float4 r2 = *(const float4*)(hrow + 32 + lg * 8);
        float4 r3 = *(const float4*)(hrow + 32 + lg * 8 + 4);
        f16x8 a0 = cvt8(r0, r1), a1 = cvt8(r2, r3);
        const int m0 = mt * 16 + lg * 4;
#pragma unroll
        for (int jt = 0; jt < 8; ++jt) {
            const int j = jt * 16 + l15;
            f32x4 acc = {0.f, 0.f, 0.f, 0.f};
            acc = MFMA16(a0, *(const f16x8*)(Wc + j * 64 + lg * 8), acc);
            acc = MFMA16(a1, *(const f16x8*)(Wc + j * 64 + 32 + lg * 8), acc);
            const float bc = biasc[j];
            if (m0 < 200) {
                f16x4 pk;
                pk[0] = (f16)(acc[0] + bc); pk[1] = (f16)(acc[1] + bc);
                pk[2] = (f16)(acc[2] + bc); pk[3] = (f16)(acc[3] + bc);
                *(f16x4*)(hT + j * 202 + m0) = pk;
            }
        }
    }
    __syncthreads();

    // ---- Hoist B-fragments (tile-invariant): wave w owns cols w*16..+16 ----
    f16x8 Bf[7];
    {
        const f16* hTp = hT + (w * 16 + l15) * 202;
#pragma unroll
        for (int ks = 0; ks < 6; ++ks)
            Bf[ks] = *(const f16x8*)(hTp + ks * 32 + lg * 8);
        Bf[6] = (lg == 0) ? *(const f16x8*)(hTp + 192) : zero8();
    }
    __syncthreads();   // hT dead -> hA may overwrite

    // ---- Phase 2: inputs = A_cat @ h_cat; 7 iters x 32 n-rows -------------
    // staging map: 3200 float4-units = 2 halves x 32 rows x 50 units
    const int hf = w >> 2;   // wave's half (cols 0-63 vs 64-127)
    int s_half[7], s_row[7], s_c4[7]; bool s_act[7];
#pragma unroll
    for (int r = 0; r < 7; ++r) {
        const int u = tid + r * 512;
        s_act[r] = u < 3200;
        const int uc = s_act[r] ? u : 0;
        s_half[r] = uc / 1600;
        const int rem = uc % 1600;
        s_row[r] = rem / 50; s_c4[r] = rem % 50;
    }

    float4 v[7];
#define P2_LOADS(T)                                                               \
    {                                                                             \
        _Pragma("unroll")                                                         \
        for (int r = 0; r < 7; ++r) if (s_act[r]) {                               \
            int grow = (T) * 32 + s_row[r];                                       \
            if (grow > 199) grow = 199;                                           \
            v[r] = *(const float4*)(Ab + (size_t)(s_half[r] * 200 + grow) * 200   \
                                    + s_c4[r] * 4);                               \
        }                                                                         \
    }
#define P2_WRITE(BUF)                                                             \
    {                                                                             \
        _Pragma("unroll")                                                         \
        for (int r = 0; r < 7; ++r) if (s_act[r]) {                               \
            f16x4 pk;                                                             \
            pk[0] = (f16)v[r].x; pk[1] = (f16)v[r].y;                             \
            pk[2] = (f16)v[r].z; pk[3] = (f16)v[r].w;                             \
            *(f16x4*)(hA + ((BUF) * 64 + s_half[r] * 32 + s_row[r]) * 202         \
                      + s_c4[r] * 4) = pk;                                        \
        }                                                                         \
    }

    P2_LOADS(0);
    P2_WRITE(0);
    P2_LOADS(1);
    __syncthreads();

    for (int t = 0; t < 7; ++t) {
#pragma unroll
        for (int s = 0; s < 2; ++s) {
            if (t == 6 && s == 1) break;      // rows 208-223 don't exist
            const f16* hAp = hA + ((size_t)(t & 1) * 64 + hf * 32 + s * 16 + l15) * 202;
            f32x4 acc = {0.f, 0.f, 0.f, 0.f};
#pragma unroll
            for (int ks = 0; ks < 7; ++ks) {
                f16x8 af;
                if (ks < 6)      af = *(const f16x8*)(hAp + ks * 32 + lg * 8);
                else if (lg == 0) af = *(const f16x8*)(hAp + 192);
                else              af = zero8();
                acc = MFMA16(af, Bf[ks], acc);
            }
#pragma unroll
            for (int r = 0; r < 4; ++r) {
                const int n = t * 32 + s * 16 + lg * 4 + r;
                if (n < 200) ib[n * 128 + w * 16 + l15] = (f16)acc[r];
            }
        }
        if (t < 6) {
            P2_WRITE((t + 1) & 1);
            if (t < 5) P2_LOADS(t + 2);
        }
        __syncthreads();
    }

    // ---- Phase 3: gi = inputs@w_ih^T, gh = hidden@w_hh^T, gates, store ----
    const int c    = w & 3;
    const int wm2  = w >> 2;
    const int hcol = c * 16 + l15;
    f16x8 Wf0[4], Wf1[4], Wf2[4];
#pragma unroll
    for (int k = 0; k < 4; ++k) {
        Wf0[k] = *(const f16x8*)(Wih + (hcol      ) * 128 + k * 32 + lg * 8);
        Wf1[k] = *(const f16x8*)(Wih + (64  + hcol) * 128 + k * 32 + lg * 8);
        Wf2[k] = *(const f16x8*)(Wih + (128 + hcol) * 128 + k * 32 + lg * 8);
    }
    f16x8 Hf0[2], Hf1[2], Hf2[2];
#pragma unroll
    for (int k = 0; k < 2; ++k) {
        Hf0[k] = *(const f16x8*)(Whh + (hcol      ) * 64 + k * 32 + lg * 8);
        Hf1[k] = *(const f16x8*)(Whh + (64  + hcol) * 64 + k * 32 + lg * 8);
        Hf2[k] = *(const f16x8*)(Whh + (128 + hcol) * 64 + k * 32 + lg * 8);
    }
    const float cAr = cstA[hcol], cAi = cstA[64 + hcol], cAn = cstA[128 + hcol];
    const float cBr = cstB[hcol], cBi = cstB[64 + hcol], cBn = cstB[128 + hcol];

    for (int t = wm2; t < 13; t += 2) {
        const int n  = t * 16 + l15;
        const int nc = n < 200 ? n : 199;
        f32x4 gir = {0.f,0.f,0.f,0.f}, gii = {0.f,0.f,0.f,0.f}, gin = {0.f,0.f,0.f,0.f};
        f32x4 ghr = {0.f,0.f,0.f,0.f}, ghi = {0.f,0.f,0.f,0.f}, ghn = {0.f,0.f,0.f,0.f};
#pragma unroll
        for (int k = 0; k < 4; ++k) {          // gi: K = 128, inp rows L2-hot
            f16x8 a = *(const f16x8*)(ib + nc * 128 + k * 32 + lg * 8);
            gir = MFMA16(a, Wf0[k], gir);
            gii = MFMA16(a, Wf1[k], gii);
            gin = MFMA16(a, Wf2[k], gin);
        }
#pragma unroll
        for (int k = 0; k < 2; ++k) {          // gh: K = 64
            const int h = k * 32 + lg * 8;
            float4 r0 = *(const float4*)(hb + nc * 64 + h);
            float4 r1 = *(const float4*)(hb + nc * 64 + h + 4);
            f16x8 a = cvt8(r0, r1);
            ghr = MFMA16(a, Hf0[k], ghr);
            ghi = MFMA16(a, Hf1[k], ghi);
            ghn = MFMA16(a, Hf2[k], ghn);
        }
#pragma unroll
        for (int r = 0; r < 4; ++r) {
            const int row = t * 16 + lg * 4 + r;
            if (row < 200) {
                const float hv = hb[row * 64 + hcol];
                const float xr = gir[r] + ghr[r] + cAr + cBr;
                const float xi = gii[r] + ghi[r] + cAi + cBi;
                const float rg = 1.0f / (1.0f + __expf(-xr));
                const float ig = 1.0f / (1.0f + __expf(-xi));
                const float xn = gin[r] + cAn + rg * (ghn[r] + cBn);
                const float e2 = __expf(2.0f * xn);
                const float ng = 1.0f - 2.0f / (e2 + 1.0f);
                ob[row * 64 + hcol] = hv + ig * (ng - hv);
            }
        }
    }
}

extern "C" void kernel_launch(void* const* d_in, const int* in_sizes, int n_in,
                              void* d_out, int out_size, void* d_ws, size_t ws_size,
                              hipStream_t stream) {
    const float* A        = (const float*)d_in[0];
    const float* hidden   = (const float*)d_in[1];
    const float* w_ih     = (const float*)d_in[2];
    const float* w_hh     = (const float*)d_in[3];
    const float* b_ih     = (const float*)d_in[4];
    const float* b_hh     = (const float*)d_in[5];
    const float* b_iah    = (const float*)d_in[6];
    const float* b_oah    = (const float*)d_in[7];
    const float* W_in     = (const float*)d_in[8];
    const float* bias_in  = (const float*)d_in[9];
    const float* W_out    = (const float*)d_in[10];
    const float* bias_out = (const float*)d_in[11];
    float* out = (float*)d_out;

    char* wsb = (char*)d_ws;
    f16* Wc      = (f16*)wsb;            // 8192 f16
    f16* Whh     = Wc + 8192;            // 12288 f16
    f16* Wih     = Whh + 12288;          // 24576 f16
    float* cstA  = (float*)(wsb + 90112);
    float* cstB  = cstA + 192;
    float* biasc = cstB + 192;
    f16* inp     = (f16*)(wsb + 92160);  // 1024*200*128 f16 = 52.4 MB

    zero_kernel<<<dim3(1), dim3(256), 0, stream>>>(cstA);
    prep_kernel<<<dim3(64), dim3(256), 0, stream>>>(
        w_ih, w_hh, b_ih, b_hh, b_iah, b_oah, W_in, bias_in, W_out, bias_out,
        Wc, Whh, Wih, cstA, cstB, biasc);
    gru_fused<<<dim3(1024), dim3(512), 0, stream>>>(
        A, hidden, Wc, Whh, Wih, cstA, cstB, biasc, inp, out);
}

// Round 6
// 177.084 us; speedup vs baseline: 1.2247x; 1.2247x over previous
//
#include <hip/hip_runtime.h>

typedef _Float16 f16;
typedef __attribute__((ext_vector_type(4))) _Float16 f16x4;
typedef __attribute__((ext_vector_type(8))) _Float16 f16x8;
typedef __attribute__((ext_vector_type(4))) float f32x4;

#define MFMA16(a, b, c) __builtin_amdgcn_mfma_f32_16x16x32_f16((a), (b), (c), 0, 0, 0)

__device__ __forceinline__ f16x8 cvt8(float4 a, float4 b) {
    f16x8 r;
    r[0] = (f16)a.x; r[1] = (f16)a.y; r[2] = (f16)a.z; r[3] = (f16)a.w;
    r[4] = (f16)b.x; r[5] = (f16)b.y; r[6] = (f16)b.z; r[7] = (f16)b.w;
    return r;
}

__device__ __forceinline__ f16x8 zero8() {
    f16x8 z;
#pragma unroll
    for (int q = 0; q < 8; ++q) z[q] = (f16)0.0f;
    return z;
}

// ---------------- pre-kernel: fp16 weights + fused bias constants into ws ----
__global__ void prep_kernel(const float* __restrict__ w_ih, const float* __restrict__ w_hh,
                            const float* __restrict__ b_ih, const float* __restrict__ b_hh,
                            const float* __restrict__ b_iah, const float* __restrict__ b_oah,
                            const float* __restrict__ W_in, const float* __restrict__ bias_in,
                            const float* __restrict__ W_out, const float* __restrict__ bias_out,
                            f16* __restrict__ Wc, f16* __restrict__ Whh, f16* __restrict__ Wih,
                            float* __restrict__ cstA, float* __restrict__ cstB,
                            float* __restrict__ biasc) {
    const int gid = blockIdx.x * 256 + threadIdx.x;
    const int gstride = gridDim.x * 256;
    for (int i = gid; i < 8192; i += gstride)
        Wc[i] = (f16)(i < 4096 ? W_in[i] : W_out[i - 4096]);
    for (int i = gid; i < 12288; i += gstride) Whh[i] = (f16)w_hh[i];   // [192][64]
    for (int i = gid; i < 24576; i += gstride) Wih[i] = (f16)w_ih[i];   // [192][128]
    for (int job = gid; job < 768; job += gstride) {
        const int g = job >> 2, q = job & 3;
        float s = (q == 0) ? b_ih[g] : 0.0f;
        const float* wr = w_ih + g * 128 + q * 32;
        for (int i = 0; i < 32; ++i)
            s += wr[i] * ((q * 32 + i < 64) ? b_iah[q * 32 + i] : b_oah[q * 32 + i - 64]);
        atomicAdd(&cstA[g], s);
    }
    for (int g = gid; g < 192; g += gstride) cstB[g] = b_hh[g];
    for (int j = gid; j < 128; j += gstride) biasc[j] = (j < 64) ? bias_in[j] : bias_out[j - 64];
}

__global__ void zero_kernel(float* __restrict__ cstA) {
    if (threadIdx.x < 192) cstA[threadIdx.x] = 0.0f;
}

// ---------------- fused main kernel: one WG (512 thr) per batch b ------------
// LDS 56576 B, aliased across phases:
//   P1:      hT  [128][200] f16 (51200)        h_cat^T
//   P2:      hA  [2][64][200] f16 (51200)      32-row double-buffered A tiles
//   P2e/P3:  inp [208][136] f16 (56576)
// Bf hoist makes hT dead -> hA aliases it. accC stays in registers.
__global__ __launch_bounds__(512, 2) void gru_fused(
    const float* __restrict__ A, const float* __restrict__ hidden,
    const f16* __restrict__ Wc, const f16* __restrict__ Whh, const f16* __restrict__ Wih,
    const float* __restrict__ cstA, const float* __restrict__ cstB,
    const float* __restrict__ biasc, float* __restrict__ out) {
    __shared__ __align__(16) char lds_raw[56576];
    f16* hT  = (f16*)lds_raw;   // [128][200]
    f16* hA  = (f16*)lds_raw;   // [2][64][200] alias
    f16* inp = (f16*)lds_raw;   // [208][136]   alias

    const int b = blockIdx.x;
    const float* Ab = A + (size_t)b * 80000;      // [400][200]
    const float* hb = hidden + (size_t)b * 12800; // [200][64]
    float* ob = out + (size_t)b * 12800;

    const int tid = threadIdx.x;
    const int w   = tid >> 6;
    const int l   = tid & 63;
    const int l15 = l & 15;
    const int lg  = l >> 4;

    // ---- Phase 1: hT[j][m] = f16(hidden[m,:]@Wc[j,:] + biasc[j]) ----
    for (int mt = w; mt < 13; mt += 8) {
        const int m  = mt * 16 + l15;
        const int mc = m < 200 ? m : 199;
        const float* hrow = hb + mc * 64;
        float4 r0 = *(const float4*)(hrow + lg * 8);
        float4 r1 = *(const float4*)(hrow + lg * 8 + 4);
        float4 r2 = *(const float4*)(hrow + 32 + lg * 8);
        float4 r3 = *(const float4*)(hrow + 32 + lg * 8 + 4);
        f16x8 a0 = cvt8(r0, r1), a1 = cvt8(r2, r3);
        const int m0 = mt * 16 + lg * 4;
#pragma unroll
        for (int jt = 0; jt < 8; ++jt) {
            const int j = jt * 16 + l15;
            f32x4 acc = {0.f, 0.f, 0.f, 0.f};
            acc = MFMA16(a0, *(const f16x8*)(Wc + j * 64 + lg * 8), acc);
            acc = MFMA16(a1, *(const f16x8*)(Wc + j * 64 + 32 + lg * 8), acc);
            const float bc = biasc[j];
            if (m0 < 200) {
                f16x4 pk;
                pk[0] = (f16)(acc[0] + bc); pk[1] = (f16)(acc[1] + bc);
                pk[2] = (f16)(acc[2] + bc); pk[3] = (f16)(acc[3] + bc);
                *(f16x4*)(hT + j * 200 + m0) = pk;
            }
        }
    }
    __syncthreads();

    // ---- Hoist tile-invariant B fragments: wave w owns output cols w*16.. ----
    f16x8 Bf[7];
    {
        const f16* hTp = hT + (w * 16 + l15) * 200;
#pragma unroll
        for (int ks = 0; ks < 6; ++ks)
            Bf[ks] = *(const f16x8*)(hTp + ks * 32 + lg * 8);
        Bf[6] = (lg == 0) ? *(const f16x8*)(hTp + 192) : zero8();
    }
    __syncthreads();   // hT dead -> hA may overwrite

    // ---- Phase 2: inputs = A_cat @ h_cat; 7 iters x 32 rows, dbuf, 1 barrier
    const int hf = w >> 2;   // wave's half (output cols 0-63 vs 64-127)

    float4 v[7];
#define P2_LOADS(T)                                                               \
    {                                                                             \
        _Pragma("unroll")                                                         \
        for (int r = 0; r < 7; ++r) {                                             \
            const int u = tid + r * 512;                                          \
            if (u < 3200) {                                                       \
                const int uh = u / 1600, rem = u % 1600;                          \
                int grow = (T) * 32 + rem / 50;                                   \
                if (grow > 199) grow = 199;                                       \
                v[r] = *(const float4*)(Ab + (size_t)(uh * 200 + grow) * 200      \
                                        + (rem % 50) * 4);                        \
            }                                                                     \
        }                                                                         \
    }
#define P2_WRITE(BUF)                                                             \
    {                                                                             \
        _Pragma("unroll")                                                         \
        for (int r = 0; r < 7; ++r) {                                             \
            const int u = tid + r * 512;                                          \
            if (u < 3200) {                                                       \
                const int uh = u / 1600, rem = u % 1600;                          \
                f16x4 pk;                                                         \
                pk[0] = (f16)v[r].x; pk[1] = (f16)v[r].y;                         \
                pk[2] = (f16)v[r].z; pk[3] = (f16)v[r].w;                         \
                *(f16x4*)(hA + ((BUF) * 64 + uh * 32 + rem / 50) * 200            \
                          + (rem % 50) * 4) = pk;                                 \
            }                                                                     \
        }                                                                         \
    }

    f32x4 accC[13];
#pragma unroll
    for (int t = 0; t < 13; ++t) accC[t] = (f32x4){0.f, 0.f, 0.f, 0.f};

    P2_LOADS(0);
    P2_WRITE(0);
    P2_LOADS(1);
    __syncthreads();

    for (int t = 0; t < 7; ++t) {
#pragma unroll
        for (int s = 0; s < 2; ++s) {
            if (t == 6 && s == 1) break;       // rows 208-223 don't exist
            const f16* hAp = hA + ((t & 1) * 64 + hf * 32 + s * 16 + l15) * 200;
            f32x4 acc = accC[2 * t + s];
#pragma unroll
            for (int ks = 0; ks < 7; ++ks) {
                f16x8 af;
                if (ks < 6)       af = *(const f16x8*)(hAp + ks * 32 + lg * 8);
                else if (lg == 0) af = *(const f16x8*)(hAp + 192);
                else              af = zero8();
                acc = MFMA16(af, Bf[ks], acc);
            }
            accC[2 * t + s] = acc;
        }
        if (t < 6) {
            P2_WRITE((t + 1) & 1);             // buffer iter t-1 finished reading
            if (t < 5) P2_LOADS(t + 2);
        }
        __syncthreads();                       // ONE barrier per iter
    }

    // spill accC -> inp LDS (hA dead)
#pragma unroll
    for (int u = 0; u < 13; ++u) {
#pragma unroll
        for (int r = 0; r < 4; ++r) {
            const int n = u * 16 + lg * 4 + r;
            if (n < 200) inp[n * 136 + w * 16 + l15] = (f16)accC[u][r];
        }
    }
    __syncthreads();

    // ---- Phase 3: gi = inputs@w_ih^T, gh = hidden@w_hh^T, gates, store ----
    const int c    = w & 3;
    const int wm2  = w >> 2;
    const int hcol = c * 16 + l15;
    f16x8 Wf0[4], Wf1[4], Wf2[4];
#pragma unroll
    for (int k = 0; k < 4; ++k) {
        Wf0[k] = *(const f16x8*)(Wih + (hcol      ) * 128 + k * 32 + lg * 8);
        Wf1[k] = *(const f16x8*)(Wih + (64  + hcol) * 128 + k * 32 + lg * 8);
        Wf2[k] = *(const f16x8*)(Wih + (128 + hcol) * 128 + k * 32 + lg * 8);
    }
    f16x8 Hf0[2], Hf1[2], Hf2[2];
#pragma unroll
    for (int k = 0; k < 2; ++k) {
        Hf0[k] = *(const f16x8*)(Whh + (hcol      ) * 64 + k * 32 + lg * 8);
        Hf1[k] = *(const f16x8*)(Whh + (64  + hcol) * 64 + k * 32 + lg * 8);
        Hf2[k] = *(const f16x8*)(Whh + (128 + hcol) * 64 + k * 32 + lg * 8);
    }
    const float cAr = cstA[hcol], cAi = cstA[64 + hcol], cAn = cstA[128 + hcol];
    const float cBr = cstB[hcol], cBi = cstB[64 + hcol], cBn = cstB[128 + hcol];

    for (int t = wm2; t < 13; t += 2) {
        const int n  = t * 16 + l15;
        const int nc = n < 200 ? n : 199;
        f32x4 gir = {0.f,0.f,0.f,0.f}, gii = {0.f,0.f,0.f,0.f}, gin = {0.f,0.f,0.f,0.f};
        f32x4 ghr = {0.f,0.f,0.f,0.f}, ghi = {0.f,0.f,0.f,0.f}, ghn = {0.f,0.f,0.f,0.f};
#pragma unroll
        for (int k = 0; k < 2; ++k) {          // gh first: issue global loads early
            const int h = k * 32 + lg * 8;
            float4 r0 = *(const float4*)(hb + nc * 64 + h);
            float4 r1 = *(const float4*)(hb + nc * 64 + h + 4);
            f16x8 a = cvt8(r0, r1);
            ghr = MFMA16(a, Hf0[k], ghr);
            ghi = MFMA16(a, Hf1[k], ghi);
            ghn = MFMA16(a, Hf2[k], ghn);
        }
#pragma unroll
        for (int k = 0; k < 4; ++k) {          // gi: K = 128, inp in LDS
            f16x8 a = *(const f16x8*)(inp + nc * 136 + k * 32 + lg * 8);
            gir = MFMA16(a, Wf0[k], gir);
            gii = MFMA16(a, Wf1[k], gii);
            gin = MFMA16(a, Wf2[k], gin);
        }
#pragma unroll
        for (int r = 0; r < 4; ++r) {
            const int row = t * 16 + lg * 4 + r;
            if (row < 200) {
                const float hv = hb[row * 64 + hcol];
                const float xr = gir[r] + ghr[r] + cAr + cBr;
                const float xi = gii[r] + ghi[r] + cAi + cBi;
                const float rg = 1.0f / (1.0f + __expf(-xr));
                const float ig = 1.0f / (1.0f + __expf(-xi));
                const float xn = gin[r] + cAn + rg * (ghn[r] + cBn);
                const float e2 = __expf(2.0f * xn);
                const float ng = 1.0f - 2.0f / (e2 + 1.0f);
                ob[row * 64 + hcol] = hv + ig * (ng - hv);
            }
        }
    }
}

extern "C" void kernel_launch(void* const* d_in, const int* in_sizes, int n_in,
                              void* d_out, int out_size, void* d_ws, size_t ws_size,
                              hipStream_t stream) {
    const float* A        = (const float*)d_in[0];
    const float* hidden   = (const float*)d_in[1];
    const float* w_ih     = (const float*)d_in[2];
    const float* w_hh     = (const float*)d_in[3];
    const float* b_ih     = (const float*)d_in[4];
    const float* b_hh     = (const float*)d_in[5];
    const float* b_iah    = (const float*)d_in[6];
    const float* b_oah    = (const float*)d_in[7];
    const float* W_in     = (const float*)d_in[8];
    const float* bias_in  = (const float*)d_in[9];
    const float* W_out    = (const float*)d_in[10];
    const float* bias_out = (const float*)d_in[11];
    float* out = (float*)d_out;

    char* wsb = (char*)d_ws;
    f16* Wc      = (f16*)wsb;            // 8192 f16
    f16* Whh     = Wc + 8192;            // 12288 f16
    f16* Wih     = Whh + 12288;          // 24576 f16
    float* cstA  = (float*)(wsb + 90112);
    float* cstB  = cstA + 192;
    float* biasc = cstB + 192;

    zero_kernel<<<dim3(1), dim3(256), 0, stream>>>(cstA);
    prep_kernel<<<dim3(64), dim3(256), 0, stream>>>(
        w_ih, w_hh, b_ih, b_hh, b_iah, b_oah, W_in, bias_in, W_out, bias_out,
        Wc, Whh, Wih, cstA, cstB, biasc);
    gru_fused<<<dim3(1024), dim3(512), 0, stream>>>(
        A, hidden, Wc, Whh, Wih, cstA, cstB, biasc, out);
}

// Round 8
// 169.285 us; speedup vs baseline: 1.2811x; 1.0461x over previous
//
#include <hip/hip_runtime.h>

typedef _Float16 f16;
typedef __attribute__((ext_vector_type(4))) _Float16 f16x4;
typedef __attribute__((ext_vector_type(8))) _Float16 f16x8;
typedef __attribute__((ext_vector_type(4))) float f32x4;

#define MFMA16(a, b, c) __builtin_amdgcn_mfma_f32_16x16x32_f16((a), (b), (c), 0, 0, 0)

__device__ __forceinline__ f16x8 cvt8(float4 a, float4 b) {
    f16x8 r;
    r[0] = (f16)a.x; r[1] = (f16)a.y; r[2] = (f16)a.z; r[3] = (f16)a.w;
    r[4] = (f16)b.x; r[5] = (f16)b.y; r[6] = (f16)b.z; r[7] = (f16)b.w;
    return r;
}

__device__ __forceinline__ f16x8 zero8() {
    f16x8 z;
#pragma unroll
    for (int q = 0; q < 8; ++q) z[q] = (f16)0.0f;
    return z;
}

// ---------------- pre-kernel: fp16 weights + fused bias constants into ws ----
__global__ void prep_kernel(const float* __restrict__ w_ih, const float* __restrict__ w_hh,
                            const float* __restrict__ b_ih, const float* __restrict__ b_hh,
                            const float* __restrict__ b_iah, const float* __restrict__ b_oah,
                            const float* __restrict__ W_in, const float* __restrict__ bias_in,
                            const float* __restrict__ W_out, const float* __restrict__ bias_out,
                            f16* __restrict__ Wc, f16* __restrict__ Whh, f16* __restrict__ Wih,
                            float* __restrict__ cstA, float* __restrict__ cstB,
                            float* __restrict__ biasc) {
    const int gid = blockIdx.x * 256 + threadIdx.x;
    const int gstride = gridDim.x * 256;
    for (int i = gid; i < 8192; i += gstride)
        Wc[i] = (f16)(i < 4096 ? W_in[i] : W_out[i - 4096]);
    for (int i = gid; i < 12288; i += gstride) Whh[i] = (f16)w_hh[i];   // [192][64]
    for (int i = gid; i < 24576; i += gstride) Wih[i] = (f16)w_ih[i];   // [192][128]
    for (int job = gid; job < 768; job += gstride) {
        const int g = job >> 2, q = job & 3;
        float s = (q == 0) ? b_ih[g] : 0.0f;
        const float* wr = w_ih + g * 128 + q * 32;
        for (int i = 0; i < 32; ++i)
            s += wr[i] * ((q * 32 + i < 64) ? b_iah[q * 32 + i] : b_oah[q * 32 + i - 64]);
        atomicAdd(&cstA[g], s);
    }
    for (int g = gid; g < 192; g += gstride) cstB[g] = b_hh[g];
    for (int j = gid; j < 128; j += gstride) biasc[j] = (j < 64) ? bias_in[j] : bias_out[j - 64];
}

__global__ void zero_kernel(float* __restrict__ cstA) {
    if (threadIdx.x < 192) cstA[threadIdx.x] = 0.0f;
}

// ---------------- fused main kernel: one WG (512 thr) per batch b ------------
// LDS 63232 B, aliased:
//   P1/hoist: hT  [128][200] f16 (51200)  h_cat^T
//   P2/P3:    inp [208][152] f16 (63232)  (152: 76 dw = 12 mod 32 -> no 8-way)
// Phase 2 streams A DIRECTLY from global (no LDS staging, no barriers).
// Rolling 2-slot prefetch with FULLY STATIC slot index: tile loop unrolled
// inside constant-bound branches so s = tt*7+k is compile-time (R7 bug was
// runtime tile loop flipping slot parity every odd-length tile).
__global__ __launch_bounds__(512, 2) void gru_fused(
    const float* __restrict__ A, const float* __restrict__ hidden,
    const f16* __restrict__ Wc, const f16* __restrict__ Whh, const f16* __restrict__ Wih,
    const float* __restrict__ cstA, const float* __restrict__ cstB,
    const float* __restrict__ biasc, float* __restrict__ out) {
    __shared__ __align__(16) char lds_raw[63232];
    f16* hT  = (f16*)lds_raw;   // [128][200]
    f16* inp = (f16*)lds_raw;   // [208][152] alias

    const int b = blockIdx.x;
    const float* Ab = A + (size_t)b * 80000;      // [400][200]
    const float* hb = hidden + (size_t)b * 12800; // [200][64]
    float* ob = out + (size_t)b * 12800;

    const int tid = threadIdx.x;
    const int w   = tid >> 6;
    const int l   = tid & 63;
    const int l15 = l & 15;
    const int lg  = l >> 4;

    // ---- Phase 1: hT[j][m] = f16(hidden[m,:]@Wc[j,:] + biasc[j]) ----
    for (int mt = w; mt < 13; mt += 8) {
        const int m  = mt * 16 + l15;
        const int mc = m < 200 ? m : 199;
        const float* hrow = hb + mc * 64;
        float4 r0 = *(const float4*)(hrow + lg * 8);
        float4 r1 = *(const float4*)(hrow + lg * 8 + 4);
        float4 r2 = *(const float4*)(hrow + 32 + lg * 8);
        float4 r3 = *(const float4*)(hrow + 32 + lg * 8 + 4);
        f16x8 a0 = cvt8(r0, r1), a1 = cvt8(r2, r3);
        const int m0 = mt * 16 + lg * 4;
#pragma unroll
        for (int jt = 0; jt < 8; ++jt) {
            const int j = jt * 16 + l15;
            f32x4 acc = {0.f, 0.f, 0.f, 0.f};
            acc = MFMA16(a0, *(const f16x8*)(Wc + j * 64 + lg * 8), acc);
            acc = MFMA16(a1, *(const f16x8*)(Wc + j * 64 + 32 + lg * 8), acc);
            const float bc = biasc[j];
            if (m0 < 200) {
                f16x4 pk;
                pk[0] = (f16)(acc[0] + bc); pk[1] = (f16)(acc[1] + bc);
                pk[2] = (f16)(acc[2] + bc); pk[3] = (f16)(acc[3] + bc);
                *(f16x4*)(hT + j * 200 + m0) = pk;
            }
        }
    }
    __syncthreads();

    // ---- Hoist B-fragments: wave w -> cols [g*32, g*32+32), 2 col-tiles ----
    const int g  = w & 3;
    const int rg = w >> 2;
    const int hf = g >> 1;   // A half (0: cols 0-63, 1: cols 64-127)
    f16x8 B0[7], B1[7];
    {
        const f16* hT0 = hT + (g * 32 + l15) * 200;
        const f16* hT1 = hT + (g * 32 + 16 + l15) * 200;
#pragma unroll
        for (int ks = 0; ks < 6; ++ks) {
            B0[ks] = *(const f16x8*)(hT0 + ks * 32 + lg * 8);
            B1[ks] = *(const f16x8*)(hT1 + ks * 32 + lg * 8);
        }
        B0[6] = (lg == 0) ? *(const f16x8*)(hT0 + 192) : zero8();
        B1[6] = (lg == 0) ? *(const f16x8*)(hT1 + 192) : zero8();
    }
    __syncthreads();   // hT dead -> inp may overwrite

    // ---- Phase 2: stream A from global, no barriers, no LDS staging ----
#define AROWP(T) (Ab + (size_t)(hf * 200 + ((((T) * 16 + l15) < 200) ? ((T) * 16 + l15) : 199)) * 200)

    float4 p[2][2];   // 2-slot rolling prefetch; ALL indices compile-time

#define PHASE2(TBEG, NT)                                                          \
    {                                                                             \
        const float* ap0 = AROWP(TBEG) + lg * 8;                                  \
        p[0][0] = *(const float4*)ap0;                                            \
        p[0][1] = *(const float4*)(ap0 + 4);                                      \
        const float* ap1 = AROWP(TBEG) + 32 + lg * 8;                             \
        p[1][0] = *(const float4*)ap1;                                            \
        p[1][1] = *(const float4*)(ap1 + 4);                                      \
        _Pragma("unroll")                                                         \
        for (int tt = 0; tt < (NT); ++tt) {                                       \
            const int t = (TBEG) + tt;                                            \
            f32x4 a0 = {0.f, 0.f, 0.f, 0.f}, a1 = {0.f, 0.f, 0.f, 0.f};           \
            _Pragma("unroll")                                                     \
            for (int k = 0; k < 7; ++k) {                                         \
                const int s = tt * 7 + k;                                         \
                float4 q0 = p[s & 1][0], q1 = p[s & 1][1];                        \
                const int ns = s + 2, nt = ns / 7, nk = ns % 7;                   \
                if (nt < (NT)) {                                                  \
                    const float* ap = AROWP((TBEG) + nt)                          \
                                      + (nk < 6 ? nk * 32 + lg * 8 : 192);        \
                    p[s & 1][0] = *(const float4*)ap;                             \
                    p[s & 1][1] = *(const float4*)(ap + 4);                       \
                }                                                                 \
                f16x8 af = (k == 6 && lg != 0) ? zero8() : cvt8(q0, q1);          \
                a0 = MFMA16(af, B0[k], a0);                                       \
                a1 = MFMA16(af, B1[k], a1);                                       \
            }                                                                     \
            _Pragma("unroll")                                                     \
            for (int r = 0; r < 4; ++r) {                                         \
                const int n = t * 16 + lg * 4 + r;                                \
                if (n < 200) {                                                    \
                    inp[n * 152 + g * 32 + l15]      = (f16)a0[r];                \
                    inp[n * 152 + g * 32 + 16 + l15] = (f16)a1[r];                \
                }                                                                 \
            }                                                                     \
        }                                                                         \
    }

    if (rg == 0) PHASE2(0, 7) else PHASE2(7, 6)
#undef PHASE2
#undef AROWP
    __syncthreads();

    // ---- Phase 3: gi = inputs@w_ih^T, gh = hidden@w_hh^T, gates, store ----
    const int c    = w & 3;
    const int wm2  = w >> 2;
    const int hcol = c * 16 + l15;
    f16x8 Wf0[4], Wf1[4], Wf2[4];
#pragma unroll
    for (int k = 0; k < 4; ++k) {
        Wf0[k] = *(const f16x8*)(Wih + (hcol      ) * 128 + k * 32 + lg * 8);
        Wf1[k] = *(const f16x8*)(Wih + (64  + hcol) * 128 + k * 32 + lg * 8);
        Wf2[k] = *(const f16x8*)(Wih + (128 + hcol) * 128 + k * 32 + lg * 8);
    }
    f16x8 Hf0[2], Hf1[2], Hf2[2];
#pragma unroll
    for (int k = 0; k < 2; ++k) {
        Hf0[k] = *(const f16x8*)(Whh + (hcol      ) * 64 + k * 32 + lg * 8);
        Hf1[k] = *(const f16x8*)(Whh + (64  + hcol) * 64 + k * 32 + lg * 8);
        Hf2[k] = *(const f16x8*)(Whh + (128 + hcol) * 64 + k * 32 + lg * 8);
    }
    const float cAr = cstA[hcol], cAi = cstA[64 + hcol], cAn = cstA[128 + hcol];
    const float cBr = cstB[hcol], cBi = cstB[64 + hcol], cBn = cstB[128 + hcol];

    for (int t = wm2; t < 13; t += 2) {
        const int n  = t * 16 + l15;
        const int nc = n < 200 ? n : 199;
        f32x4 gir = {0.f,0.f,0.f,0.f}, gii = {0.f,0.f,0.f,0.f}, gin = {0.f,0.f,0.f,0.f};
        f32x4 ghr = {0.f,0.f,0.f,0.f}, ghi = {0.f,0.f,0.f,0.f}, ghn = {0.f,0.f,0.f,0.f};
#pragma unroll
        for (int k = 0; k < 2; ++k) {          // gh first: global loads issue early
            const int h = k * 32 + lg * 8;
            float4 r0 = *(const float4*)(hb + nc * 64 + h);
            float4 r1 = *(const float4*)(hb + nc * 64 + h + 4);
            f16x8 a = cvt8(r0, r1);
            ghr = MFMA16(a, Hf0[k], ghr);
            ghi = MFMA16(a, Hf1[k], ghi);
            ghn = MFMA16(a, Hf2[k], ghn);
        }
#pragma unroll
        for (int k = 0; k < 4; ++k) {          // gi: K = 128, inp in LDS
            f16x8 a = *(const f16x8*)(inp + nc * 152 + k * 32 + lg * 8);
            gir = MFMA16(a, Wf0[k], gir);
            gii = MFMA16(a, Wf1[k], gii);
            gin = MFMA16(a, Wf2[k], gin);
        }
#pragma unroll
        for (int r = 0; r < 4; ++r) {
            const int row = t * 16 + lg * 4 + r;
            if (row < 200) {
                const float hv = hb[row * 64 + hcol];
                const float xr = gir[r] + ghr[r] + cAr + cBr;
                const float xi = gii[r] + ghi[r] + cAi + cBi;
                const float rg2 = 1.0f / (1.0f + __expf(-xr));
                const float ig = 1.0f / (1.0f + __expf(-xi));
                const float xn = gin[r] + cAn + rg2 * (ghn[r] + cBn);
                const float e2 = __expf(2.0f * xn);
                const float ng = 1.0f - 2.0f / (e2 + 1.0f);
                ob[row * 64 + hcol] = hv + ig * (ng - hv);
            }
        }
    }
}

extern "C" void kernel_launch(void* const* d_in, const int* in_sizes, int n_in,
                              void* d_out, int out_size, void* d_ws, size_t ws_size,
                              hipStream_t stream) {
    const float* A        = (const float*)d_in[0];
    const float* hidden   = (const float*)d_in[1];
    const float* w_ih     = (const float*)d_in[2];
    const float* w_hh     = (const float*)d_in[3];
    const float* b_ih     = (const float*)d_in[4];
    const float* b_hh     = (const float*)d_in[5];
    const float* b_iah    = (const float*)d_in[6];
    const float* b_oah    = (const float*)d_in[7];
    const float* W_in     = (const float*)d_in[8];
    const float* bias_in  = (const float*)d_in[9];
    const float* W_out    = (const float*)d_in[10];
    const float* bias_out = (const float*)d_in[11];
    float* out = (float*)d_out;

    char* wsb = (char*)d_ws;
    f16* Wc      = (f16*)wsb;            // 8192 f16
    f16* Whh     = Wc + 8192;            // 12288 f16
    f16* Wih     = Whh + 12288;          // 24576 f16
    float* cstA  = (float*)(wsb + 90112);
    float* cstB  = cstA + 192;
    float* biasc = cstB + 192;

    zero_kernel<<<dim3(1), dim3(256), 0, stream>>>(cstA);
    prep_kernel<<<dim3(64), dim3(256), 0, stream>>>(
        w_ih, w_hh, b_ih, b_hh, b_iah, b_oah, W_in, bias_in, W_out, bias_out,
        Wc, Whh, Wih, cstA, cstB, biasc);
    gru_fused<<<dim3(1024), dim3(512), 0, stream>>>(
        A, hidden, Wc, Whh, Wih, cstA, cstB, biasc, out);
}